// Round 2
// baseline (35.979 us; speedup 1.0000x reference)
//
#include <hip/hip_runtime.h>
#include <math.h>

// SubGL aggregation kernel.
// out[b,l,:] = normalize(user_emb[seq[b,l]] + sum_n w[b,l,n]*user_emb[nbr[b,l,n]])
// w[b,l,n]   = dot(rel_emb[rel_neigh[b,l,n]], softmax(weight_b))

#define BB 64
#define LL 200
#define NN 32
#define DD 128
#define RR 3

// 32 lanes per (b,l) pair; each lane owns one float4 chunk (4 dims of 128).
// 256-thread block = 8 pairs. Grid = B*L/8 = 1600 blocks.
//
// Broadcast of (idx, w) within a group goes through LDS (uniform-address
// ds_read_b128, 2 neighbors per read) instead of 64 ds_swizzle ops.
// Gather loop runs in batches of 8 so ~8 KB/wave of loads stay in flight.
__global__ __launch_bounds__(256) void subgl_kernel(
    const int* __restrict__ sequence,
    const int* __restrict__ seq_neighbor,
    const int* __restrict__ rel_neigh,
    const float* __restrict__ user_emb,
    const float* __restrict__ rel_emb,
    const float* __restrict__ weight_b,
    float* __restrict__ out)
{
    const int tid   = threadIdx.x;
    const int chunk = tid & 31;
    const int pair  = tid >> 5;
    const int bl    = blockIdx.x * 8 + pair;   // 1600*8 = 12800 exact

    __shared__ int2 s_iw[8][32];   // .x = neighbor idx, .y = weight bits

    // beta = softmax(weight_b) -- 3 scalars, trivial per-thread
    const float wb0 = weight_b[0], wb1 = weight_b[1], wb2 = weight_b[2];
    const float mx  = fmaxf(fmaxf(wb0, wb1), wb2);
    const float e0 = __expf(wb0 - mx), e1 = __expf(wb1 - mx), e2 = __expf(wb2 - mx);
    const float inv = 1.0f / (e0 + e1 + e2);
    const float b0 = e0 * inv, b1 = e1 * inv, b2 = e2 * inv;

    // lane n computes neighbor n's index and mixing weight (coalesced loads)
    const int nbr = seq_neighbor[bl * NN + chunk];
    const int rel = rel_neigh[bl * NN + chunk];
    const float w = rel_emb[rel * RR + 0] * b0
                  + rel_emb[rel * RR + 1] * b1
                  + rel_emb[rel * RR + 2] * b2;
    int2 p; p.x = nbr; p.y = __float_as_int(w);
    s_iw[pair][chunk] = p;

    const float4* __restrict__ emb4 = (const float4*)user_emb;

    const int seq_idx = sequence[bl];
    float4 acc = emb4[(size_t)seq_idx * (DD / 4) + chunk];

    __syncthreads();   // order LDS write -> read (cheap, once per block)

    #pragma unroll
    for (int k = 0; k < NN; k += 8) {
        // 8 (idx,w) pairs via 4 uniform-address 16B LDS reads
        const int4 q0 = *(const int4*)&s_iw[pair][k + 0];
        const int4 q1 = *(const int4*)&s_iw[pair][k + 2];
        const int4 q2 = *(const int4*)&s_iw[pair][k + 4];
        const int4 q3 = *(const int4*)&s_iw[pair][k + 6];

        const float4 v0 = emb4[(size_t)q0.x * (DD / 4) + chunk];
        const float4 v1 = emb4[(size_t)q0.z * (DD / 4) + chunk];
        const float4 v2 = emb4[(size_t)q1.x * (DD / 4) + chunk];
        const float4 v3 = emb4[(size_t)q1.z * (DD / 4) + chunk];
        const float4 v4 = emb4[(size_t)q2.x * (DD / 4) + chunk];
        const float4 v5 = emb4[(size_t)q2.z * (DD / 4) + chunk];
        const float4 v6 = emb4[(size_t)q3.x * (DD / 4) + chunk];
        const float4 v7 = emb4[(size_t)q3.z * (DD / 4) + chunk];

        const float w0 = __int_as_float(q0.y), w1 = __int_as_float(q0.w);
        const float w2 = __int_as_float(q1.y), w3 = __int_as_float(q1.w);
        const float w4 = __int_as_float(q2.y), w5 = __int_as_float(q2.w);
        const float w6 = __int_as_float(q3.y), w7 = __int_as_float(q3.w);

        acc.x += w0*v0.x; acc.y += w0*v0.y; acc.z += w0*v0.z; acc.w += w0*v0.w;
        acc.x += w1*v1.x; acc.y += w1*v1.y; acc.z += w1*v1.z; acc.w += w1*v1.w;
        acc.x += w2*v2.x; acc.y += w2*v2.y; acc.z += w2*v2.z; acc.w += w2*v2.w;
        acc.x += w3*v3.x; acc.y += w3*v3.y; acc.z += w3*v3.z; acc.w += w3*v3.w;
        acc.x += w4*v4.x; acc.y += w4*v4.y; acc.z += w4*v4.z; acc.w += w4*v4.w;
        acc.x += w5*v5.x; acc.y += w5*v5.y; acc.z += w5*v5.z; acc.w += w5*v5.w;
        acc.x += w6*v6.x; acc.y += w6*v6.y; acc.z += w6*v6.z; acc.w += w6*v6.w;
        acc.x += w7*v7.x; acc.y += w7*v7.y; acc.z += w7*v7.z; acc.w += w7*v7.w;
    }

    // L2 norm over 128 dims = reduce acc.acc across the 32-lane group
    float ss = acc.x*acc.x + acc.y*acc.y + acc.z*acc.z + acc.w*acc.w;
    #pragma unroll
    for (int m = 16; m >= 1; m >>= 1)
        ss += __shfl_xor(ss, m, 32);

    const float rn = 1.0f / fmaxf(sqrtf(ss), 1e-12f);

    float4 o;
    o.x = acc.x * rn; o.y = acc.y * rn; o.z = acc.z * rn; o.w = acc.w * rn;
    ((float4*)out)[(size_t)bl * (DD / 4) + chunk] = o;
}

extern "C" void kernel_launch(void* const* d_in, const int* in_sizes, int n_in,
                              void* d_out, int out_size, void* d_ws, size_t ws_size,
                              hipStream_t stream) {
    const int*   sequence     = (const int*)d_in[0];
    const int*   seq_neighbor = (const int*)d_in[1];
    const int*   rel_neigh    = (const int*)d_in[2];
    const float* user_emb     = (const float*)d_in[3];
    const float* rel_emb      = (const float*)d_in[4];
    const float* weight_b     = (const float*)d_in[5];
    float*       out          = (float*)d_out;

    const int grid = (BB * LL) / 8;   // 1600 blocks, 8 pairs each
    subgl_kernel<<<grid, 256, 0, stream>>>(sequence, seq_neighbor, rel_neigh,
                                           user_emb, rel_emb, weight_b, out);
}

// Round 3
// 33.376 us; speedup vs baseline: 1.0780x; 1.0780x over previous
//
#include <hip/hip_runtime.h>
#include <math.h>

// SubGL aggregation kernel.
// out[b,l,:] = normalize(user_emb[seq[b,l]] + sum_n w[b,l,n]*user_emb[nbr[b,l,n]])
// w[b,l,n]   = dot(rel_emb[rel_neigh[b,l,n]], softmax(weight_b))
//
// Strategy: bytes-bound at ~6.4 TB/s effective (R1/R2 both 35.5-36us, matching
// 226 MB / 6.4 TB/s). Cut bytes: stage the 51.2 MB f32 table as bf16 (25.6 MB)
// in d_ws each launch, gather 256B rows instead of 512B. 195 MB total.

#define BB 64
#define LL 200
#define NN 32
#define DD 128
#define RR 3
#define USERS 100000

static __device__ __forceinline__ unsigned short f2bf(float f) {
    unsigned u = __float_as_uint(f);
    unsigned r = u + 0x7FFFu + ((u >> 16) & 1u);   // round-to-nearest-even
    return (unsigned short)(r >> 16);
}
static __device__ __forceinline__ unsigned pack2(float lo, float hi) {
    return (unsigned)f2bf(lo) | ((unsigned)f2bf(hi) << 16);
}
static __device__ __forceinline__ float bf_lo(unsigned v) {
    return __uint_as_float(v << 16);
}
static __device__ __forceinline__ float bf_hi(unsigned v) {
    return __uint_as_float(v & 0xFFFF0000u);
}

// ---- convert: f32 table -> bf16 table (streaming, 8 elems/thread) ----
__global__ __launch_bounds__(256) void convert_bf16_kernel(
    const float* __restrict__ in, unsigned* __restrict__ out, int n8)
{
    int i = blockIdx.x * blockDim.x + threadIdx.x;
    if (i >= n8) return;
    const float4* p = (const float4*)in;
    float4 a = p[(size_t)i * 2 + 0];
    float4 b = p[(size_t)i * 2 + 1];
    uint4 o;
    o.x = pack2(a.x, a.y);
    o.y = pack2(a.z, a.w);
    o.z = pack2(b.x, b.y);
    o.w = pack2(b.z, b.w);
    ((uint4*)out)[i] = o;
}

// ---- gather from bf16 table: 32 lanes/pair, each lane 4 dims (8B loads) ----
__global__ __launch_bounds__(256) void subgl_bf16_kernel(
    const int* __restrict__ sequence,
    const int* __restrict__ seq_neighbor,
    const int* __restrict__ rel_neigh,
    const unsigned* __restrict__ emb_bf,   // [USERS][DD/2] packed bf16 pairs
    const float* __restrict__ rel_emb,
    const float* __restrict__ weight_b,
    float* __restrict__ out)
{
    const int tid   = threadIdx.x;
    const int chunk = tid & 31;
    const int pair  = tid >> 5;
    const int bl    = blockIdx.x * 8 + pair;   // 1600*8 = 12800 exact

    // beta = softmax(weight_b)
    const float wb0 = weight_b[0], wb1 = weight_b[1], wb2 = weight_b[2];
    const float mx  = fmaxf(fmaxf(wb0, wb1), wb2);
    const float e0 = __expf(wb0 - mx), e1 = __expf(wb1 - mx), e2 = __expf(wb2 - mx);
    const float inv = 1.0f / (e0 + e1 + e2);
    const float b0 = e0 * inv, b1 = e1 * inv, b2 = e2 * inv;

    // lane n owns neighbor n's index + mixing weight
    const int nbr_own = seq_neighbor[bl * NN + chunk];
    const int rel_own = rel_neigh[bl * NN + chunk];
    const float w_own = rel_emb[rel_own * RR + 0] * b0
                      + rel_emb[rel_own * RR + 1] * b1
                      + rel_emb[rel_own * RR + 2] * b2;

    const uint2* __restrict__ emb2 = (const uint2*)emb_bf;  // row = 32 x uint2

    // accumulator starts with the sequence row (bf16 table)
    const int seq_idx = sequence[bl];
    const uint2 sv = emb2[(size_t)seq_idx * 32 + chunk];
    float4 acc;
    acc.x = bf_lo(sv.x); acc.y = bf_hi(sv.x);
    acc.z = bf_lo(sv.y); acc.w = bf_hi(sv.y);

    #pragma unroll
    for (int k = 0; k < NN; k += 8) {
        int   i0 = __shfl(nbr_own, k + 0, 32), i1 = __shfl(nbr_own, k + 1, 32);
        int   i2 = __shfl(nbr_own, k + 2, 32), i3 = __shfl(nbr_own, k + 3, 32);
        int   i4 = __shfl(nbr_own, k + 4, 32), i5 = __shfl(nbr_own, k + 5, 32);
        int   i6 = __shfl(nbr_own, k + 6, 32), i7 = __shfl(nbr_own, k + 7, 32);
        float w0 = __shfl(w_own, k + 0, 32), w1 = __shfl(w_own, k + 1, 32);
        float w2 = __shfl(w_own, k + 2, 32), w3 = __shfl(w_own, k + 3, 32);
        float w4 = __shfl(w_own, k + 4, 32), w5 = __shfl(w_own, k + 5, 32);
        float w6 = __shfl(w_own, k + 6, 32), w7 = __shfl(w_own, k + 7, 32);

        const uint2 v0 = emb2[(size_t)i0 * 32 + chunk];
        const uint2 v1 = emb2[(size_t)i1 * 32 + chunk];
        const uint2 v2 = emb2[(size_t)i2 * 32 + chunk];
        const uint2 v3 = emb2[(size_t)i3 * 32 + chunk];
        const uint2 v4 = emb2[(size_t)i4 * 32 + chunk];
        const uint2 v5 = emb2[(size_t)i5 * 32 + chunk];
        const uint2 v6 = emb2[(size_t)i6 * 32 + chunk];
        const uint2 v7 = emb2[(size_t)i7 * 32 + chunk];

        acc.x += w0*bf_lo(v0.x); acc.y += w0*bf_hi(v0.x); acc.z += w0*bf_lo(v0.y); acc.w += w0*bf_hi(v0.y);
        acc.x += w1*bf_lo(v1.x); acc.y += w1*bf_hi(v1.x); acc.z += w1*bf_lo(v1.y); acc.w += w1*bf_hi(v1.y);
        acc.x += w2*bf_lo(v2.x); acc.y += w2*bf_hi(v2.x); acc.z += w2*bf_lo(v2.y); acc.w += w2*bf_hi(v2.y);
        acc.x += w3*bf_lo(v3.x); acc.y += w3*bf_hi(v3.x); acc.z += w3*bf_lo(v3.y); acc.w += w3*bf_hi(v3.y);
        acc.x += w4*bf_lo(v4.x); acc.y += w4*bf_hi(v4.x); acc.z += w4*bf_lo(v4.y); acc.w += w4*bf_hi(v4.y);
        acc.x += w5*bf_lo(v5.x); acc.y += w5*bf_hi(v5.x); acc.z += w5*bf_lo(v5.y); acc.w += w5*bf_hi(v5.y);
        acc.x += w6*bf_lo(v6.x); acc.y += w6*bf_hi(v6.x); acc.z += w6*bf_lo(v6.y); acc.w += w6*bf_hi(v6.y);
        acc.x += w7*bf_lo(v7.x); acc.y += w7*bf_hi(v7.x); acc.z += w7*bf_lo(v7.y); acc.w += w7*bf_hi(v7.y);
    }

    float ss = acc.x*acc.x + acc.y*acc.y + acc.z*acc.z + acc.w*acc.w;
    #pragma unroll
    for (int m = 16; m >= 1; m >>= 1)
        ss += __shfl_xor(ss, m, 32);

    const float rn = 1.0f / fmaxf(sqrtf(ss), 1e-12f);

    float4 o;
    o.x = acc.x * rn; o.y = acc.y * rn; o.z = acc.z * rn; o.w = acc.w * rn;
    ((float4*)out)[(size_t)bl * (DD / 4) + chunk] = o;
}

// ---- fallback: f32 gather (proven 35.5us) if workspace too small ----
__global__ __launch_bounds__(256) void subgl_f32_kernel(
    const int* __restrict__ sequence,
    const int* __restrict__ seq_neighbor,
    const int* __restrict__ rel_neigh,
    const float* __restrict__ user_emb,
    const float* __restrict__ rel_emb,
    const float* __restrict__ weight_b,
    float* __restrict__ out)
{
    const int tid   = threadIdx.x;
    const int chunk = tid & 31;
    const int pair  = tid >> 5;
    const int bl    = blockIdx.x * 8 + pair;

    const float wb0 = weight_b[0], wb1 = weight_b[1], wb2 = weight_b[2];
    const float mx  = fmaxf(fmaxf(wb0, wb1), wb2);
    const float e0 = __expf(wb0 - mx), e1 = __expf(wb1 - mx), e2 = __expf(wb2 - mx);
    const float inv = 1.0f / (e0 + e1 + e2);
    const float b0 = e0 * inv, b1 = e1 * inv, b2 = e2 * inv;

    const int nbr_own = seq_neighbor[bl * NN + chunk];
    const int rel_own = rel_neigh[bl * NN + chunk];
    const float w_own = rel_emb[rel_own * RR + 0] * b0
                      + rel_emb[rel_own * RR + 1] * b1
                      + rel_emb[rel_own * RR + 2] * b2;

    const float4* __restrict__ emb4 = (const float4*)user_emb;
    const int seq_idx = sequence[bl];
    float4 acc = emb4[(size_t)seq_idx * (DD / 4) + chunk];

    #pragma unroll 4
    for (int n = 0; n < NN; ++n) {
        const int   idx = __shfl(nbr_own, n, 32);
        const float w   = __shfl(w_own,  n, 32);
        const float4 v  = emb4[(size_t)idx * (DD / 4) + chunk];
        acc.x += w * v.x; acc.y += w * v.y; acc.z += w * v.z; acc.w += w * v.w;
    }

    float ss = acc.x*acc.x + acc.y*acc.y + acc.z*acc.z + acc.w*acc.w;
    #pragma unroll
    for (int m = 16; m >= 1; m >>= 1)
        ss += __shfl_xor(ss, m, 32);
    const float rn = 1.0f / fmaxf(sqrtf(ss), 1e-12f);

    float4 o;
    o.x = acc.x * rn; o.y = acc.y * rn; o.z = acc.z * rn; o.w = acc.w * rn;
    ((float4*)out)[(size_t)bl * (DD / 4) + chunk] = o;
}

extern "C" void kernel_launch(void* const* d_in, const int* in_sizes, int n_in,
                              void* d_out, int out_size, void* d_ws, size_t ws_size,
                              hipStream_t stream) {
    const int*   sequence     = (const int*)d_in[0];
    const int*   seq_neighbor = (const int*)d_in[1];
    const int*   rel_neigh    = (const int*)d_in[2];
    const float* user_emb     = (const float*)d_in[3];
    const float* rel_emb      = (const float*)d_in[4];
    const float* weight_b     = (const float*)d_in[5];
    float*       out          = (float*)d_out;

    const size_t bf16_bytes = (size_t)USERS * DD * 2;   // 25.6 MB
    const int grid = (BB * LL) / 8;                     // 1600 blocks

    if (ws_size >= bf16_bytes) {
        unsigned* emb_bf = (unsigned*)d_ws;
        const int n8 = USERS * DD / 8;                  // 1.6M threads
        convert_bf16_kernel<<<(n8 + 255) / 256, 256, 0, stream>>>(
            user_emb, emb_bf, n8);
        subgl_bf16_kernel<<<grid, 256, 0, stream>>>(
            sequence, seq_neighbor, rel_neigh, emb_bf, rel_emb, weight_b, out);
    } else {
        subgl_f32_kernel<<<grid, 256, 0, stream>>>(
            sequence, seq_neighbor, rel_neigh, user_emb, rel_emb, weight_b, out);
    }
}